// Round 7
// baseline (565.896 us; speedup 1.0000x reference)
//
#include <hip/hip_runtime.h>
#include <hip/hip_bf16.h>
#include <hip/hip_fp16.h>

#define H_DIM 128
#define BN_EPS 1e-5f

typedef _Float16 half8 __attribute__((ext_vector_type(8)));
typedef float floatx4 __attribute__((ext_vector_type(4)));

// ---------------- degree ----------------
__global__ void degree_kernel(const int* __restrict__ dst, int* __restrict__ deg, int E_) {
    int i = blockIdx.x * blockDim.x + threadIdx.x;
    if (i < E_) atomicAdd(&deg[dst[i]], 1);
}

// ---------------- exclusive scan (3-kernel), dinv fused into pass 1 ----------------
__global__ void scan_block_kernel(const int* __restrict__ deg, float* __restrict__ dinv,
                                  int* __restrict__ rowptr, int* __restrict__ bsum, int N_) {
    __shared__ int sh[256];
    int i = blockIdx.x * 256 + threadIdx.x;
    int v = (i < N_) ? deg[i] : 0;
    if (i < N_) dinv[i] = rsqrtf((float)v + 1.0f);
    sh[threadIdx.x] = v;
    __syncthreads();
    for (int off = 1; off < 256; off <<= 1) {
        int t = (threadIdx.x >= off) ? sh[threadIdx.x - off] : 0;
        __syncthreads();
        sh[threadIdx.x] += t;
        __syncthreads();
    }
    if (i < N_) rowptr[i] = sh[threadIdx.x] - v;   // exclusive
    if (threadIdx.x == 255) bsum[blockIdx.x] = sh[255];
}

__global__ void scan_bsums_kernel(const int* __restrict__ bsum, int* __restrict__ boff, int nb) {
    __shared__ int sh[512];
    int v = (threadIdx.x < nb) ? bsum[threadIdx.x] : 0;
    sh[threadIdx.x] = v;
    __syncthreads();
    for (int off = 1; off < 512; off <<= 1) {
        int t = (threadIdx.x >= off) ? sh[threadIdx.x - off] : 0;
        __syncthreads();
        sh[threadIdx.x] += t;
        __syncthreads();
    }
    if (threadIdx.x < nb) boff[threadIdx.x] = sh[threadIdx.x] - v;  // exclusive
}

__global__ void scan_add_kernel(int* __restrict__ rowptr, const int* __restrict__ boff,
                                int N_, int E_) {
    int i = blockIdx.x * 256 + threadIdx.x;
    if (i < N_) rowptr[i] += boff[blockIdx.x];
    if (i == 0) rowptr[N_] = E_;
}

// ---------------- CSR fill, XCD-binned by dst bucket ----------------
__global__ void csr_fill_kernel(const int* __restrict__ src, const int* __restrict__ dst,
                                const int* __restrict__ rowptr, int* __restrict__ cursor,
                                int* __restrict__ cols, int E_, int N_, int shift) {
    int b = blockIdx.x & 7;
    if (((N_ - 1) >> shift) < b) return;          // bucket never occurs
    int i = (blockIdx.x >> 3) * blockDim.x + threadIdx.x;
    if (i < E_) {
        int d = dst[i];
        if ((d >> shift) == b) {
            int p = rowptr[d] + atomicAdd(&cursor[d], 1);
            cols[p] = src[i];
        }
    }
}

// ---------------- MFMA fragment helpers ----------------
__device__ inline half8 a_frag_f32(const float* Xr, int k0) {
    float4 v0 = *(const float4*)(Xr + k0);
    float4 v1 = *(const float4*)(Xr + k0 + 4);
    half8 a;
    a[0] = (_Float16)v0.x; a[1] = (_Float16)v0.y; a[2] = (_Float16)v0.z; a[3] = (_Float16)v0.w;
    a[4] = (_Float16)v1.x; a[5] = (_Float16)v1.y; a[6] = (_Float16)v1.z; a[7] = (_Float16)v1.w;
    return a;
}
__device__ inline half8 a_frag_f16_bn(const _Float16* Xr, int k0,
                                      const float* A, const float* B) {
    half8 r = *(const half8*)(Xr + k0);
    half8 o;
#pragma unroll
    for (int u = 0; u < 8; ++u)
        o[u] = (_Float16)fmaxf(fmaf((float)r[u], A[k0 + u], B[k0 + u]), 0.f);
    return o;
}

// ---------------- MFMA GEMM: Y[N,128] = dinv .* (bnrelu(X)[N,128] @ W[128,128]) ----------------
// BN A/B computed in-block from gsum/gsq (bn_finalize fused). 2 row-tiles per block.
template<bool BN, typename InT>
__global__ __launch_bounds__(256) void gemm_mfma_kernel(
    const InT* __restrict__ X, const float* __restrict__ W,
    const float* __restrict__ gsum, const float* __restrict__ gsq,
    const float* __restrict__ gamma, const float* __restrict__ beta,
    const float* __restrict__ dinv,
    _Float16* __restrict__ Y, int N_, int ntiles, float inv_n)
{
    __shared__ _Float16 Wf[32 * 64 * 8];   // 32 KB: [nt*4+kb][lane][j]
    __shared__ float Abn[128], Bbn[128];

    const int tid = threadIdx.x;
    // ---- stage W[128][128] f32 -> LDS fragment order ----
    for (int idx = tid; idx < 128 * 32; idx += 256) {
        int k = idx >> 5;                   // 0..127
        int n0 = (idx & 31) * 4;
        float4 w = *(const float4*)(W + k * 128 + n0);
        int kb = k >> 5, q = (k >> 3) & 3, j = k & 7;
#pragma unroll
        for (int u = 0; u < 4; ++u) {
            int n = n0 + u;
            int lane = (n & 15) | (q << 4);
            Wf[((((n >> 4) * 4 + kb) * 64 + lane) << 3) + j] = (_Float16)((&w.x)[u]);
        }
    }
    if constexpr (BN) {
        if (tid < 128) {
            float mean = gsum[tid] * inv_n;
            float var = gsq[tid] * inv_n - mean * mean;
            float a = rsqrtf(var + BN_EPS) * gamma[tid];
            Abn[tid] = a;
            Bbn[tid] = beta[tid] - mean * a;
        }
    }
    __syncthreads();

    const int wv = tid >> 6, lane = tid & 63;
    const int m = lane & 15, q = lane >> 4;

    for (int t = blockIdx.x; t < ntiles; t += gridDim.x) {
        const int row0 = t * 64 + wv * 16;
        int arow = row0 + m;
        if (arow >= N_) arow = N_ - 1;
        const InT* Xr = X + (size_t)arow * H_DIM;

        half8 a[4];
#pragma unroll
        for (int kb = 0; kb < 4; ++kb) {
            int k0 = kb * 32 + q * 8;
            if constexpr (BN) a[kb] = a_frag_f16_bn((const _Float16*)Xr, k0, Abn, Bbn);
            else              a[kb] = a_frag_f32((const float*)Xr, k0);
        }

        floatx4 acc[8];
#pragma unroll
        for (int nt = 0; nt < 8; ++nt) acc[nt] = (floatx4){0.f, 0.f, 0.f, 0.f};

#pragma unroll
        for (int nt = 0; nt < 8; ++nt) {
#pragma unroll
            for (int kb = 0; kb < 4; ++kb) {
                half8 b = *(const half8*)&Wf[(((nt * 4 + kb) * 64 + lane) << 3)];
                acc[nt] = __builtin_amdgcn_mfma_f32_16x16x32_f16(a[kb], b, acc[nt], 0, 0, 0);
            }
        }

#pragma unroll
        for (int r = 0; r < 4; ++r) {
            int row = row0 + q * 4 + r;
            if (row < N_) {
                float ds = dinv[row];
                _Float16* Yr = Y + (size_t)row * H_DIM + m;
#pragma unroll
                for (int nt = 0; nt < 8; ++nt)
                    Yr[nt * 16] = (_Float16)(ds * acc[nt][r]);
            }
        }
    }
}

// ---------------- MFMA readout: Y[N,40] = bnrelu(X)[N,128] @ Wr[128,40] + br ----------------
__global__ __launch_bounds__(256) void readout_mfma_kernel(
    const _Float16* __restrict__ X, const float* __restrict__ W,   // [128, OUTC]
    const float* __restrict__ gsum, const float* __restrict__ gsq,
    const float* __restrict__ gamma, const float* __restrict__ beta,
    const float* __restrict__ br,
    float* __restrict__ Y, int N_, int OUTC, int ntiles, float inv_n)
{
    __shared__ _Float16 Wf[12 * 64 * 8];   // 12 KB: 3 n-tiles (48 cols padded)
    __shared__ float Abn[128], Bbn[128];

    const int tid = threadIdx.x;
    for (int idx = tid; idx < 128 * 64; idx += 256) {
        int k = idx >> 6, n = idx & 63;
        if (n < 48) {
            float w = (n < OUTC) ? W[k * OUTC + n] : 0.f;
            int kb = k >> 5, q = (k >> 3) & 3, j = k & 7;
            int lane = (n & 15) | (q << 4);
            Wf[((((n >> 4) * 4 + kb) * 64 + lane) << 3) + j] = (_Float16)w;
        }
    }
    if (tid < 128) {
        float mean = gsum[tid] * inv_n;
        float var = gsq[tid] * inv_n - mean * mean;
        float a = rsqrtf(var + BN_EPS) * gamma[tid];
        Abn[tid] = a;
        Bbn[tid] = beta[tid] - mean * a;
    }
    __syncthreads();

    const int wv = tid >> 6, lane = tid & 63;
    const int m = lane & 15, q = lane >> 4;

    for (int t = blockIdx.x; t < ntiles; t += gridDim.x) {
        const int row0 = t * 64 + wv * 16;
        int arow = row0 + m;
        if (arow >= N_) arow = N_ - 1;
        const _Float16* Xr = X + (size_t)arow * H_DIM;

        half8 a[4];
#pragma unroll
        for (int kb = 0; kb < 4; ++kb)
            a[kb] = a_frag_f16_bn(Xr, kb * 32 + q * 8, Abn, Bbn);

        floatx4 acc[3];
#pragma unroll
        for (int nt = 0; nt < 3; ++nt) acc[nt] = (floatx4){0.f, 0.f, 0.f, 0.f};

#pragma unroll
        for (int nt = 0; nt < 3; ++nt) {
#pragma unroll
            for (int kb = 0; kb < 4; ++kb) {
                half8 b = *(const half8*)&Wf[(((nt * 4 + kb) * 64 + lane) << 3)];
                acc[nt] = __builtin_amdgcn_mfma_f32_16x16x32_f16(a[kb], b, acc[nt], 0, 0, 0);
            }
        }

#pragma unroll
        for (int nt = 0; nt < 3; ++nt) {
            int col = nt * 16 + m;
            if (col < OUTC) {
                float bb = br[col];
#pragma unroll
                for (int r = 0; r < 4; ++r) {
                    int row = row0 + q * 4 + r;
                    if (row < N_)
                        Y[(size_t)row * OUTC + col] = acc[nt][r] + bb;
                }
            }
        }
    }
}

// ---------------- aggregation: out[d] = dinv[d]*(g[d] + sum g[src_e]) + bias ----------------
// one wave per node, half2/lane, packed fp16 accum, 16 gathers in flight
__global__ __launch_bounds__(256) void aggregate_kernel(
    const __half2* __restrict__ Gp,           // [N][64] half2 (dinv-scaled h)
    const int* __restrict__ rowptr,
    const int* __restrict__ cols,
    const float* __restrict__ dinv, const float* __restrict__ bias,
    __half2* __restrict__ out, int N_)
{
    int wave = threadIdx.x >> 6;
    int lane = threadIdx.x & 63;
    int n = blockIdx.x * 4 + wave;
    if (n >= N_) return;

    const __half2 z = __float2half2_rn(0.f);
    __half2 acc[8];
    acc[0] = Gp[(size_t)n * 64 + lane];       // self term
#pragma unroll
    for (int u = 1; u < 8; ++u) acc[u] = z;

    int e = rowptr[n];
    const int e1 = rowptr[n + 1];
    for (; e + 15 < e1; e += 16) {
        __half2 h[16];
#pragma unroll
        for (int u = 0; u < 16; ++u) h[u] = Gp[(size_t)cols[e + u] * 64 + lane];
#pragma unroll
        for (int u = 0; u < 8; ++u) acc[u] = __hadd2(acc[u], h[u]);
#pragma unroll
        for (int u = 0; u < 8; ++u) acc[u] = __hadd2(acc[u], h[u + 8]);
    }
    for (; e + 7 < e1; e += 8) {
        __half2 h[8];
#pragma unroll
        for (int u = 0; u < 8; ++u) h[u] = Gp[(size_t)cols[e + u] * 64 + lane];
#pragma unroll
        for (int u = 0; u < 8; ++u) acc[u] = __hadd2(acc[u], h[u]);
    }
    for (; e < e1; ++e)
        acc[0] = __hadd2(acc[0], Gp[(size_t)cols[e] * 64 + lane]);

    __half2 p0 = __hadd2(__hadd2(acc[0], acc[1]), __hadd2(acc[2], acc[3]));
    __half2 p1 = __hadd2(__hadd2(acc[4], acc[5]), __hadd2(acc[6], acc[7]));
    float2 f0 = __half22float2(p0);
    float2 f1 = __half22float2(p1);
    float di = dinv[n];
    int c = lane * 2;
    float o0 = fmaf(di, f0.x + f1.x, bias[c]);
    float o1 = fmaf(di, f0.y + f1.y, bias[c + 1]);
    out[(size_t)n * 64 + lane] = __floats2half2_rn(o0, o1);
}

// ---------------- BN stats: wave streams full rows, register accum, block combine ----------------
__global__ __launch_bounds__(256) void bn_stats_kernel(
    const __half2* __restrict__ X, float* __restrict__ gsum, float* __restrict__ gsq,
    int N_, int stride)
{
    __shared__ float ssum[4][128], ssq[4][128];
    const int wave = threadIdx.x >> 6;
    const int lane = threadIdx.x & 63;
    float r0 = 0.f, r1 = 0.f, q0 = 0.f, q1 = 0.f;
    for (int n = blockIdx.x * 4 + wave; n < N_; n += stride) {
        float2 v = __half22float2(X[(size_t)n * 64 + lane]);
        r0 += v.x; r1 += v.y;
        q0 = fmaf(v.x, v.x, q0); q1 = fmaf(v.y, v.y, q1);
    }
    int c = lane * 2;
    ssum[wave][c] = r0; ssum[wave][c + 1] = r1;
    ssq[wave][c]  = q0; ssq[wave][c + 1]  = q1;
    __syncthreads();
    if (threadIdx.x < 128) {
        int k = threadIdx.x;
        float s = (ssum[0][k] + ssum[1][k]) + (ssum[2][k] + ssum[3][k]);
        float q = (ssq[0][k] + ssq[1][k]) + (ssq[2][k] + ssq[3][k]);
        atomicAdd(&gsum[k], s);
        atomicAdd(&gsq[k], q);
    }
}

// ---------------- launch ----------------
extern "C" void kernel_launch(void* const* d_in, const int* in_sizes, int n_in,
                              void* d_out, int out_size, void* d_ws, size_t ws_size,
                              hipStream_t stream) {
    const float* x   = (const float*)d_in[0];
    const int* esrc  = (const int*)d_in[1];
    const int* edst  = (const int*)d_in[2];
    const float* W1  = (const float*)d_in[3];
    const float* b1  = (const float*)d_in[4];
    const float* g1  = (const float*)d_in[5];
    const float* bt1 = (const float*)d_in[6];
    const float* W2  = (const float*)d_in[7];
    const float* b2  = (const float*)d_in[8];
    const float* g2  = (const float*)d_in[9];
    const float* bt2 = (const float*)d_in[10];
    const float* Wr  = (const float*)d_in[11];
    const float* br  = (const float*)d_in[12];

    const int N_ = in_sizes[0] / H_DIM;     // 100000
    const int E_ = in_sizes[1];             // 1600000
    const int OUTC = out_size / N_;         // 40
    const float inv_n = 1.0f / (float)N_;

    char* p = (char*)d_ws;
    auto alloc = [&](size_t bytes) -> void* {
        void* r = (void*)p;
        p += (bytes + 255) & ~(size_t)255;
        return r;
    };
    __half* tmpA = (__half*)alloc((size_t)N_ * H_DIM * 2);
    __half* tmpB = (__half*)alloc((size_t)N_ * H_DIM * 2);
    int*   cols  = (int*)  alloc((size_t)E_ * 4);
    int*   rowptr= (int*)  alloc((size_t)(N_ + 1) * 4);
    // zero-region: degcur (2N ints) + bn sums (512 floats) contiguous, single memset
    size_t degcur_sz = ((size_t)2 * N_ * 4 + 255) & ~(size_t)255;
    int*   degcur= (int*)  alloc((size_t)2 * N_ * 4);
    float* bnbuf = (float*)alloc(4 * 128 * 4);
    int*   deg   = degcur;
    int*   cursor= degcur + N_;
    float* sum1 = bnbuf,       *sq1 = bnbuf + 128;
    float* sum2 = bnbuf + 256, *sq2 = bnbuf + 384;
    float* dinv  = (float*)alloc((size_t)N_ * 4);
    int*   bsum  = (int*)  alloc(4096);
    int*   boff  = (int*)  alloc(4096);

    hipMemsetAsync(degcur, 0, degcur_sz + 4 * 128 * 4, stream);  // deg+cursor+bn sums

    const int nb = (N_ + 255) / 256;
    const int eb = (E_ + 255) / 256;
    const int ntiles64 = (N_ + 63) / 64;
    const int gemm_grid = (ntiles64 + 1) / 2;   // 2 tiles per block, reuse staged W

    int shift = 0;                           // buckets (d>>shift) in 0..7
    while (((N_ - 1) >> shift) > 7) ++shift; // N=100000 -> shift=14, buckets 0..6

    const int BN_BLOCKS = 1024;
    const int BN_STRIDE = BN_BLOCKS * 4;

    degree_kernel<<<eb, 256, 0, stream>>>(edst, deg, E_);
    scan_block_kernel<<<nb, 256, 0, stream>>>(deg, dinv, rowptr, bsum, N_);
    scan_bsums_kernel<<<1, 512, 0, stream>>>(bsum, boff, nb);
    scan_add_kernel<<<nb, 256, 0, stream>>>(rowptr, boff, N_, E_);
    csr_fill_kernel<<<eb * 8, 256, 0, stream>>>(esrc, edst, rowptr, cursor, cols, E_, N_, shift);

    // layer 1: g1 = dinv .* (x @ W1)   (f32 in, fp16 out, MFMA)
    gemm_mfma_kernel<false, float><<<gemm_grid, 256, 0, stream>>>(
        x, W1, nullptr, nullptr, nullptr, nullptr, dinv,
        (_Float16*)tmpA, N_, ntiles64, inv_n);
    aggregate_kernel<<<(N_ + 3) / 4, 256, 0, stream>>>(
        (const __half2*)tmpA, rowptr, cols, dinv, b1, (__half2*)tmpB, N_);
    bn_stats_kernel<<<BN_BLOCKS, 256, 0, stream>>>(
        (const __half2*)tmpB, sum1, sq1, N_, BN_STRIDE);

    // layer 2: g2 = dinv .* (bnrelu(h1) @ W2)   (fp16 in/out, MFMA, BN-finalize fused)
    gemm_mfma_kernel<true, _Float16><<<gemm_grid, 256, 0, stream>>>(
        (const _Float16*)tmpB, W2, sum1, sq1, g1, bt1, dinv,
        (_Float16*)tmpA, N_, ntiles64, inv_n);
    aggregate_kernel<<<(N_ + 3) / 4, 256, 0, stream>>>(
        (const __half2*)tmpA, rowptr, cols, dinv, b2, (__half2*)tmpB, N_);
    bn_stats_kernel<<<BN_BLOCKS, 256, 0, stream>>>(
        (const __half2*)tmpB, sum2, sq2, N_, BN_STRIDE);

    // readout (MFMA, BN-finalize + bias fused, f32 out)
    readout_mfma_kernel<<<gemm_grid, 256, 0, stream>>>(
        (const _Float16*)tmpB, Wr, sum2, sq2, g2, bt2, br,
        (float*)d_out, N_, OUTC, ntiles64, inv_n);
}